// Round 4
// baseline (815.897 us; speedup 1.0000x reference)
//
#include <hip/hip_runtime.h>
#include <cstdint>

namespace {
constexpr int kN = 50000;          // nodes per encoder
constexpr int kE = 200000;         // directed edges per encoder (pre self-loop)
constexpr int kE2 = kE + kN;       // with self loops (per encoder)
constexpr int kG = 256;            // graphs per encoder
constexpr float kNegSlope = 0.2f;
}

using half8   = __attribute__((ext_vector_type(8))) _Float16;
using floatx4 = __attribute__((ext_vector_type(4))) float;

__device__ __forceinline__ void gld_lds16(const void* g, void* l) {
  __builtin_amdgcn_global_load_lds(
      (const __attribute__((address_space(1))) unsigned int*)g,
      (__attribute__((address_space(3))) unsigned int*)l, 16, 0, 0);
}

// fast exp: e^x = 2^(x*log2(e)) via hardware v_exp_f32 (no libm call)
__device__ __forceinline__ float fexp(float x) {
  return __builtin_amdgcn_exp2f(x * 1.44269504088896f);
}

// ---------------- fp16 MFMA GEMM: C[M,N] = A[M,K] @ B[K,N] -----------
// R15 ring schedule (T3+T4+T5): 4-slot LDS ring, prefetch distance 3,
// counted vmcnt (never 0 in loop), setprio around MFMA clusters.
// R16: HEADS>0 fuses the GAT attention dots into the epilogue — h is
// already in acc registers, so <h_row, a_src> costs 8 FMA + a 16-lane
// shfl reduce + one f32 atomicAdd per row into per-layer asrc/adst
// tables (pre-zeroed in prep). This deletes the per-EDGE dot+reduce in
// gat_agg (was recomputed out_degree~5 times per node and ~half its
// VALU work; agg VALUBusy was 57%).
template <int OUTF16, int BN, int CT, int HEADS>
__global__ __launch_bounds__(512, 2) void gemm_ring(
    const _Float16* __restrict__ A, const _Float16* __restrict__ B,
    void* __restrict__ Cv, const float* __restrict__ av_src,
    const float* __restrict__ av_dst, float* __restrict__ aS,
    float* __restrict__ aD, int M, int N, int K) {
  constexpr int ASL = 1024;                // A slots/tile (256 rows x 32k x 2B /16)
  constexpr int BSL = BN * 4;              // B slots/tile (1024 or 512)
  constexpr int SLOT = (ASL + BSL) * 16;   // 32KB or 24KB
  constexpr int LPT = (ASL + BSL) / 512;   // loads/thread/tile: 4 or 3
  constexpr int WN = (BN == 256) ? 4 : 2;  // waves along N
  constexpr int WM = 8 / WN;
  constexpr int WTM = 256 / WM;            // 128 or 64
  constexpr int WTN = BN / WN;             // 64
  constexpr int MI = WTM / 16;             // 8 or 4
  constexpr int NI = WTN / 16;             // 4
  __shared__ alignas(16) char smem[4 * SLOT];  // 128KB or 96KB ring
  const int t = threadIdx.x;
  const int w = t >> 6, l = t & 63;
  const int x = blockIdx.x & 7, s = blockIdx.x >> 3;
  const int col = (CT == 1) ? 0 : (s & (CT - 1));
  const int rt = ((CT == 1) ? s : (s >> 1)) * 8 + x;
  const int bm = rt * 256;
  const int bn = col * BN;
  if (bm >= M) return;  // padded row-tiles: whole block exits (no barrier)
  const int wr = w / WN, wc = w % WN;
  const int quad = l >> 4, lrow = l & 15;

  floatx4 acc[MI][NI];
#pragma unroll
  for (int mi = 0; mi < MI; ++mi)
#pragma unroll
    for (int ni = 0; ni < NI; ++ni) acc[mi][ni] = (floatx4){0.f, 0.f, 0.f, 0.f};

  // stage tile kt's A-part (2 loads) / B-part (LPT-2 loads) into ring slot
  auto stageA = [&](int kt) {
    char* buf = smem + (size_t)(kt & 3) * SLOT;
    int k0 = kt * 32;
    k0 = (k0 > K - 32) ? (K - 32) : k0;  // clamp: beyond-NT garbage stays in-bounds
#pragma unroll
    for (int i = 0; i < 2; ++i) {
      const int sl = i * 512 + t;
      const int row = ((sl >> 6) << 4) + (sl & 15);
      const int q = (sl >> 4) & 3;
      int ga = bm + row;
      ga = (ga < M) ? ga : (M - 1);      // clamp: keep lanes active
      gld_lds16(A + (size_t)ga * K + k0 + q * 8, buf + sl * 16);
    }
  };
  auto stageB = [&](int kt) {
    char* buf = smem + (size_t)(kt & 3) * SLOT + ASL * 16;
    int k0 = kt * 32;
    k0 = (k0 > K - 32) ? (K - 32) : k0;
#pragma unroll
    for (int i = 0; i < LPT - 2; ++i) {
      const int sl = i * 512 + t;
      const int row = ((sl >> 6) << 4) + (sl & 15);
      const int q = (sl >> 4) & 3;
      gld_lds16(B + (size_t)(bn + row) * K + k0 + q * 8, buf + sl * 16);
    }
  };

  // prologue: tiles 0,1,2 in flight (3*LPT loads)
  stageA(0); stageB(0);
  stageA(1); stageB(1);
  stageA(2); stageB(2);

  const int NT = K >> 5;
  for (int kt = 0; kt < NT; ++kt) {
    char* bufc = smem + (size_t)(kt & 3) * SLOT;
    // ---- phase A ----
    stageA(kt + 3);  // 2 loads of tile kt+3 (slot of finished tile kt-1)
    if constexpr (BN == 256)
      asm volatile("s_waitcnt vmcnt(10)" ::: "memory");  // tile kt's 4 landed
    else
      asm volatile("s_waitcnt vmcnt(8)" ::: "memory");   // tile kt's 3 landed
    __builtin_amdgcn_s_barrier();        // all waves: slot[kt&3] ready
    asm volatile("" ::: "memory");
    half8 fa[MI], fb[NI];
#pragma unroll
    for (int ni = 0; ni < NI; ++ni)
      fb[ni] = *(const half8*)(bufc + ASL * 16 + ((wc * NI + ni) << 10) + l * 16);
#pragma unroll
    for (int mi = 0; mi < MI / 2; ++mi)
      fa[mi] = *(const half8*)(bufc + ((wr * MI + mi) << 10) + l * 16);
    __builtin_amdgcn_s_setprio(1);
#pragma unroll
    for (int mi = 0; mi < MI / 2; ++mi)
#pragma unroll
      for (int ni = 0; ni < NI; ++ni)
        acc[mi][ni] = __builtin_amdgcn_mfma_f32_16x16x32_f16(
            fa[mi], fb[ni], acc[mi][ni], 0, 0, 0);
    __builtin_amdgcn_s_setprio(0);
    // ---- phase B ----
    stageB(kt + 3);  // remaining loads of tile kt+3
#pragma unroll
    for (int mi = MI / 2; mi < MI; ++mi)
      fa[mi] = *(const half8*)(bufc + ((wr * MI + mi) << 10) + l * 16);
    __builtin_amdgcn_s_setprio(1);
#pragma unroll
    for (int mi = MI / 2; mi < MI; ++mi)
#pragma unroll
      for (int ni = 0; ni < NI; ++ni)
        acc[mi][ni] = __builtin_amdgcn_mfma_f32_16x16x32_f16(
            fa[mi], fb[ni], acc[mi][ni], 0, 0, 0);
    __builtin_amdgcn_s_setprio(0);
    asm volatile("" ::: "memory");
    __builtin_amdgcn_s_barrier();        // slot[kt&3] reusable for kt+4
  }
  asm volatile("s_waitcnt vmcnt(0)" ::: "memory");  // drain garbage prefetches
  // epilogue: C/D layout col=lane&15, row=quad*4+reg
  const int colbase = bn + wc * WTN + lrow;
  float asc[NI], adc[NI];
  if constexpr (HEADS > 0) {
#pragma unroll
    for (int ni = 0; ni < NI; ++ni) {
      asc[ni] = av_src[colbase + ni * 16];  // a vectors indexed by flat col
      adc[ni] = av_dst[colbase + ni * 16];
    }
  }
  const int head = (HEADS > 1) ? ((bn + wc * WTN) >> 7) : 0;  // 128 ch/head
#pragma unroll
  for (int mi = 0; mi < MI; ++mi) {
    const int rbase = bm + wr * WTM + mi * 16 + quad * 4;
#pragma unroll
    for (int r = 0; r < 4; ++r) {
      const int grow = rbase + r;
      if (grow < M) {
        if constexpr (OUTF16) {
          _Float16* C = (_Float16*)Cv;
#pragma unroll
          for (int ni = 0; ni < NI; ++ni)
            C[(size_t)grow * N + colbase + ni * 16] = (_Float16)acc[mi][ni][r];
        } else {
          float* C = (float*)Cv;
#pragma unroll
          for (int ni = 0; ni < NI; ++ni)
            C[(size_t)grow * N + colbase + ni * 16] = acc[mi][ni][r];
        }
      }
      if constexpr (HEADS > 0) {
        float ps = 0.f, pd = 0.f;
#pragma unroll
        for (int ni = 0; ni < NI; ++ni) {
          ps = fmaf(acc[mi][ni][r], asc[ni], ps);
          pd = fmaf(acc[mi][ni][r], adc[ni], pd);
        }
        // reduce across the 16-lane column group (uniform grow per group)
#pragma unroll
        for (int off = 1; off < 16; off <<= 1) {
          ps += __shfl_xor(ps, off);
          pd += __shfl_xor(pd, off);
        }
        if (lrow == 0 && grow < M) {
          atomicAdd(aS + (size_t)grow * HEADS + head, ps);
          atomicAdd(aD + (size_t)grow * HEADS + head, pd);
        }
      }
    }
  }
}

// ------- all three weight transposes + f16 casts in one kernel --------
__global__ void wt_split_all(const float* __restrict__ W1, _Float16* Th1,
                             const float* __restrict__ W2, _Float16* Th2,
                             const float* __restrict__ W3, _Float16* Th3) {
  int idx = blockIdx.x * blockDim.x + threadIdx.x;
  const float* W;
  _Float16* Th;
  int K, N;
  if (idx < 64 * 512) {
    W = W1; Th = Th1; K = 64; N = 512;
  } else if (idx < 64 * 512 + 512 * 512) {
    idx -= 64 * 512;
    W = W2; Th = Th2; K = 512; N = 512;
  } else if (idx < 64 * 512 + 512 * 512 + 512 * 128) {
    idx -= 64 * 512 + 512 * 512;
    W = W3; Th = Th3; K = 512; N = 128;
  } else {
    return;
  }
  const int k = idx / N;
  const int n = idx - k * N;
  Th[n * K + k] = (_Float16)W[idx];
}

// --- combined prep: x casts + cnt=1 + total=0 + zero alpha tables -----
__global__ void prep2(const float* __restrict__ x0, const float* __restrict__ x1,
                      _Float16* __restrict__ Xh, int* __restrict__ cnt,
                      int* __restrict__ total, float* __restrict__ alpha,
                      int an) {
  const int idx = blockIdx.x * blockDim.x + threadIdx.x;
  const int half = kN * 64;
  if (idx < half) Xh[idx] = (_Float16)x0[idx];
  else if (idx < 2 * half) Xh[idx] = (_Float16)x1[idx - half];
  if (idx < 2 * kN) cnt[idx] = 1;  // the self loop
  if (idx < an) alpha[idx] = 0.f;  // asrc/adst accumulators (all 3 layers)
  if (idx == 0) *total = 0;
}
// ------- single-encoder prep (fallback path) --------------------------
__global__ void prep(const float* __restrict__ X, _Float16* __restrict__ Xh,
                     int* __restrict__ cnt, int* __restrict__ total, int nsplit,
                     int n, float* __restrict__ alpha, int an) {
  const int idx = blockIdx.x * blockDim.x + threadIdx.x;
  if (idx < nsplit) Xh[idx] = (_Float16)X[idx];
  if (idx < n) cnt[idx] = 1;
  if (idx < an) alpha[idx] = 0.f;
  if (idx == 0) *total = 0;
}

// ---------------- CSR (by dst) build ----------------------------------
__global__ void count_edges2(const int* __restrict__ d0, const int* __restrict__ d1,
                             int* __restrict__ cnt) {
  const int i = blockIdx.x * blockDim.x + threadIdx.x;
  if (i < kE) atomicAdd(&cnt[d0[i]], 1);
  else if (i < 2 * kE) atomicAdd(&cnt[d1[i - kE] + kN], 1);
}
__global__ void fill_edges2(const int* __restrict__ s0, const int* __restrict__ d0,
                            const int* __restrict__ s1, const int* __restrict__ d1,
                            int* __restrict__ cursor, int* __restrict__ csr) {
  const int i = blockIdx.x * blockDim.x + threadIdx.x;
  if (i < kE) {
    const int p = atomicAdd(&cursor[d0[i]], 1);
    csr[p] = s0[i];
  } else if (i < 2 * kE) {
    const int j = i - kE;
    const int p = atomicAdd(&cursor[d1[j] + kN], 1);
    csr[p] = s1[j] + kN;
  }
}
__global__ void count_edges(const int* __restrict__ dst, int* __restrict__ cnt,
                            int ne) {
  const int i = blockIdx.x * blockDim.x + threadIdx.x;
  if (i < ne) atomicAdd(&cnt[dst[i]], 1);
}
__global__ void fill_edges(const int* __restrict__ src, const int* __restrict__ dst,
                           int* __restrict__ cursor, int* __restrict__ csr, int ne) {
  const int i = blockIdx.x * blockDim.x + threadIdx.x;
  if (i < ne) {
    const int p = atomicAdd(&cursor[dst[i]], 1);
    csr[p] = src[i];
  }
}
__global__ void alloc_ranges(const int* __restrict__ cnt, int* __restrict__ start,
                             int* __restrict__ cursor, int* __restrict__ total,
                             int* __restrict__ csr, int n) {
  const int i = blockIdx.x * blockDim.x + threadIdx.x;
  const int lane = threadIdx.x & 63;
  const int v = (i < n) ? cnt[i] : 0;
  int sc = v;
#pragma unroll
  for (int off = 1; off < 64; off <<= 1) {
    const int t = __shfl_up(sc, off);
    if (lane >= off) sc += t;
  }
  const int wtot = __shfl(sc, 63);
  int base = 0;
  if (lane == 63) base = atomicAdd(total, wtot);
  base = __shfl(base, 63);
  const int st = base + sc - v;
  if (i < n) {
    start[i] = st;
    cursor[i] = st + 1;
    csr[st] = i;  // self loop first
  }
}

// ---------------- GAT aggregate, layers 1-2 (f16 h) -------------------
// R16: attention dots precomputed by the GEMM epilogue (asrc/adst per
// node/head). Per edge: scalar asrc gather + leaky + exp + 8 mixed
// FMAs — no cvt array, no shfl reduce (was ~30 VALU/edge, now ~13).
__global__ void gat_agg4(const _Float16* __restrict__ h,
                         const float* __restrict__ asrc,
                         const float* __restrict__ adst,
                         const int* __restrict__ start, const int* __restrict__ cnt,
                         const int* __restrict__ csr_src,
                         const float* __restrict__ bias,
                         _Float16* __restrict__ outH, int n_nodes) {
  const int gtid = blockIdx.x * blockDim.x + threadIdx.x;
  const int node = gtid >> 6;
  const int lane = threadIdx.x & 63;
  if (node >= n_nodes) return;
  const int ch = lane * 8;
  const int head = lane >> 4;
  const int s = start[node];
  const int c = cnt[node];
  const float ad = adst[node * 4 + head];
  float d0 = 0.f, d1 = 0.f;
  float a0[8], a1[8];
#pragma unroll
  for (int j = 0; j < 8; ++j) { a0[j] = 0.f; a1[j] = 0.f; }
  int i = 0;
  for (; i + 2 <= c; i += 2) {
    const int s0 = csr_src[s + i];
    const int s1 = csr_src[s + i + 1];
    float e0 = asrc[s0 * 4 + head] + ad;
    float e1 = asrc[s1 * 4 + head] + ad;
    e0 = (e0 > 0.f) ? e0 : kNegSlope * e0;
    e1 = (e1 > 0.f) ? e1 : kNegSlope * e1;
    const float w0 = fexp(e0);
    const float w1 = fexp(e1);
    const half8 v0 = *(const half8*)(h + (size_t)s0 * 512 + ch);
    const half8 v1 = *(const half8*)(h + (size_t)s1 * 512 + ch);
    d0 += w0;
    d1 += w1;
#pragma unroll
    for (int j = 0; j < 8; ++j) {
      a0[j] = fmaf(w0, (float)v0[j], a0[j]);
      a1[j] = fmaf(w1, (float)v1[j], a1[j]);
    }
  }
  if (i < c) {
    const int s0 = csr_src[s + i];
    float e0 = asrc[s0 * 4 + head] + ad;
    e0 = (e0 > 0.f) ? e0 : kNegSlope * e0;
    const float w0 = fexp(e0);
    const half8 v0 = *(const half8*)(h + (size_t)s0 * 512 + ch);
    d0 += w0;
#pragma unroll
    for (int j = 0; j < 8; ++j) a0[j] = fmaf(w0, (float)v0[j], a0[j]);
  }
  const float inv = 1.f / (d0 + d1 + 1e-16f);
  half8 H;
#pragma unroll
  for (int j = 0; j < 8; ++j) {
    float v = (a0[j] + a1[j]) * inv + bias[ch + j];
    v = (v > 0.f) ? v : (fexp(v) - 1.f);  // elu via hw exp
    H[j] = (_Float16)v;
  }
  *(half8*)(outH + (size_t)node * 512 + ch) = H;
}

// ---------- GAT aggregate, layer 3 (H=1, fp32, precomputed dots) ------
__global__ void gat_agg_l3(const float* __restrict__ h,
                           const float* __restrict__ asrc,
                           const float* __restrict__ adst,
                           const int* __restrict__ start, const int* __restrict__ cnt,
                           const int* __restrict__ csr_src,
                           const float* __restrict__ bias,
                           float* __restrict__ out, int n_nodes) {
  const int gtid = blockIdx.x * blockDim.x + threadIdx.x;
  const int node = gtid >> 6;
  const int lane = threadIdx.x & 63;
  if (node >= n_nodes) return;
  const int s = start[node];
  const int c = cnt[node];
  const float ad = adst[node];
  float2 a0 = make_float2(0.f, 0.f);
  float2 a1 = make_float2(0.f, 0.f);
  float d0 = 0.f, d1 = 0.f;
  int i = 0;
  for (; i + 2 <= c; i += 2) {
    const int s0 = csr_src[s + i];
    const int s1 = csr_src[s + i + 1];
    float e0 = asrc[s0] + ad;
    float e1 = asrc[s1] + ad;
    e0 = (e0 > 0.f) ? e0 : kNegSlope * e0;
    e1 = (e1 > 0.f) ? e1 : kNegSlope * e1;
    const float w0 = fexp(e0);
    const float w1 = fexp(e1);
    const float2 v0 = *(const float2*)(h + (size_t)s0 * 128 + lane * 2);
    const float2 v1 = *(const float2*)(h + (size_t)s1 * 128 + lane * 2);
    d0 += w0;
    d1 += w1;
    a0.x = fmaf(w0, v0.x, a0.x); a1.x = fmaf(w1, v1.x, a1.x);
    a0.y = fmaf(w0, v0.y, a0.y); a1.y = fmaf(w1, v1.y, a1.y);
  }
  if (i < c) {
    const int s0 = csr_src[s + i];
    float e0 = asrc[s0] + ad;
    e0 = (e0 > 0.f) ? e0 : kNegSlope * e0;
    const float w0 = fexp(e0);
    const float2 v0 = *(const float2*)(h + (size_t)s0 * 128 + lane * 2);
    d0 += w0;
    a0.x = fmaf(w0, v0.x, a0.x);
    a0.y = fmaf(w0, v0.y, a0.y);
  }
  const float inv = 1.f / (d0 + d1 + 1e-16f);
  *(float2*)(out + (size_t)node * 128 + lane * 2) =
      make_float2((a0.x + a1.x) * inv + bias[lane * 2],
                  (a0.y + a1.y) * inv + bias[lane * 2 + 1]);
}

// ------- global max pool over sorted batch (both encoders, 1 launch) ---
__global__ void pool_max2(const float* __restrict__ x, const int* __restrict__ bt1,
                          const int* __restrict__ bt2, float* __restrict__ emb) {
  __shared__ int lohi[2];
  const int enc = blockIdx.x >> 8;
  const int g = blockIdx.x & 255;
  const int* batch = enc ? bt2 : bt1;
  const float* xx = x + (size_t)enc * kN * 128;
  if (threadIdx.x == 0) {
    int lo = 0, hi = kN;
    while (lo < hi) {
      const int mid = (lo + hi) >> 1;
      if (batch[mid] < g) lo = mid + 1; else hi = mid;
    }
    lohi[0] = lo;
    hi = kN;
    while (lo < hi) {
      const int mid = (lo + hi) >> 1;
      if (batch[mid] < g + 1) lo = mid + 1; else hi = mid;
    }
    lohi[1] = lo;
  }
  __syncthreads();
  const int lo = lohi[0], hi = lohi[1];
  const int c = threadIdx.x;  // 128 channels
  float m = -1e30f;
  for (int nid = lo; nid < hi; ++nid) m = fmaxf(m, xx[(size_t)nid * 128 + c]);
  emb[(size_t)blockIdx.x * 128 + c] = (lo < hi) ? m : 0.f;
}
// ------- single-encoder pool (fallback path) --------------------------
__global__ void pool_max(const float* __restrict__ x, const int* __restrict__ batch,
                         float* __restrict__ emb, int n_nodes) {
  __shared__ int lohi[2];
  const int g = blockIdx.x;
  if (threadIdx.x == 0) {
    int lo = 0, hi = n_nodes;
    while (lo < hi) {
      const int mid = (lo + hi) >> 1;
      if (batch[mid] < g) lo = mid + 1; else hi = mid;
    }
    lohi[0] = lo;
    hi = n_nodes;
    while (lo < hi) {
      const int mid = (lo + hi) >> 1;
      if (batch[mid] < g + 1) lo = mid + 1; else hi = mid;
    }
    lohi[1] = lo;
  }
  __syncthreads();
  const int lo = lohi[0], hi = lohi[1];
  const int c = threadIdx.x;  // 128 channels
  float m = -1e30f;
  for (int nid = lo; nid < hi; ++nid) m = fmaxf(m, x[(size_t)nid * 128 + c]);
  emb[g * 128 + c] = (lo < hi) ? m : 0.f;
}

// ---------------- final MLP head --------------------------------------
__global__ void mlp_head(const float* __restrict__ e1, const float* __restrict__ e2,
                         const float* __restrict__ mw1, const float* __restrict__ mb1,
                         const float* __restrict__ mw2, const float* __restrict__ mb2,
                         float* __restrict__ out) {
  __shared__ float z[256];
  __shared__ float red[128];
  const int g = blockIdx.x;
  const int j = threadIdx.x;  // 128
  z[j] = e1[g * 128 + j];
  z[j + 128] = e2[g * 128 + j];
  __syncthreads();
  float acc = mb1[j];
  for (int k = 0; k < 256; ++k) acc = fmaf(z[k], mw1[k * 128 + j], acc);
  acc = fmaxf(acc, 0.f) * mw2[j];
  red[j] = acc;
  __syncthreads();
  for (int s = 64; s > 0; s >>= 1) {
    if (j < s) red[j] += red[j + s];
    __syncthreads();
  }
  if (j == 0) out[g] = red[0] + mb2[0];
}

// ---------------- launcher --------------------------------------------
namespace {
struct Bufs {
  _Float16 *R1h, *R2h;
  float *R1f, *R2f;
  float *alpha;                       // 18*M floats: aS1 aD1 aS2 aD2 aS3 aD3
  int *cnt, *start, *cursor, *csr, *total;
  _Float16 *Wth1, *Wth2, *Wth3;
  float* emb;
  size_t need;
};

Bufs plan(void* d_ws, int M, int E) {
  Bufs b;
  char* w = (char*)d_ws;
  size_t off = 0;
  auto take = [&](size_t bytes) -> void* {
    void* p = w + off;
    off += (bytes + 255) & ~(size_t)255;
    return p;
  };
  b.R1h = (_Float16*)take((size_t)M * 512 * 2);  // f16 activations
  b.R1f = (float*)b.R1h;                         // layer-3 out alias [M,128]
  b.R2h = (_Float16*)take((size_t)M * 512 * 2);  // h f16; l3 fp32 alias
  b.R2f = (float*)b.R2h;
  b.alpha = (float*)take((size_t)M * 18 * 4);    // per-layer asrc/adst tables
  b.cnt = (int*)take((size_t)M * 4);
  b.start = (int*)take((size_t)M * 4);
  b.cursor = (int*)take((size_t)M * 4);
  b.csr = (int*)take((size_t)E * 4);
  b.total = (int*)take(256);
  b.Wth1 = (_Float16*)take((size_t)64 * 512 * 2);
  b.Wth2 = (_Float16*)take((size_t)512 * 512 * 2);
  b.Wth3 = (_Float16*)take((size_t)512 * 128 * 2);
  b.emb = (float*)take((size_t)2 * kG * 128 * 4);
  b.need = off;
  return b;
}

void run_layers(const Bufs& b, void* const* d_in, int M, hipStream_t stream) {
  const float* as1 = (const float*)d_in[7];
  const float* ad1 = (const float*)d_in[8];
  const float* b1 = (const float*)d_in[9];
  const float* as2 = (const float*)d_in[11];
  const float* ad2 = (const float*)d_in[12];
  const float* b2 = (const float*)d_in[13];
  const float* as3 = (const float*)d_in[15];
  const float* ad3 = (const float*)d_in[16];
  const float* b3 = (const float*)d_in[17];
  float* aS1 = b.alpha;
  float* aD1 = b.alpha + (size_t)M * 4;
  float* aS2 = b.alpha + (size_t)M * 8;
  float* aD2 = b.alpha + (size_t)M * 12;
  float* aS3 = b.alpha + (size_t)M * 16;
  float* aD3 = b.alpha + (size_t)M * 17;
  const int nodeBlocks = (M * 64) / 256;  // 1 wave/node
  const int MT = (M + 255) / 256;         // 256-row tiles
  const int SP = (MT + 7) / 8;            // row-tile groups of 8 (XCD map)

  // layer 1: [M,64] @ [64,512], h -> f16 (A1h aliases R1h)
  gemm_ring<1, 256, 2, 4><<<SP * 16, 512, 0, stream>>>(
      b.R1h, b.Wth1, b.R2h, as1, ad1, aS1, aD1, M, 512, 64);
  gat_agg4<<<nodeBlocks, 256, 0, stream>>>(b.R2h, aS1, aD1, b.start, b.cnt,
                                           b.csr, b1, b.R1h, M);
  // layer 2: [M,512] @ [512,512], h -> f16
  gemm_ring<1, 256, 2, 4><<<SP * 16, 512, 0, stream>>>(
      b.R1h, b.Wth2, b.R2h, as2, ad2, aS2, aD2, M, 512, 512);
  gat_agg4<<<nodeBlocks, 256, 0, stream>>>(b.R2h, aS2, aD2, b.start, b.cnt,
                                           b.csr, b2, b.R1h, M);
  // layer 3: [M,512] @ [512,128], H=1, no elu, fp32 out
  gemm_ring<0, 128, 1, 1><<<SP * 8, 512, 0, stream>>>(
      b.R1h, b.Wth3, b.R2f, as3, ad3, aS3, aD3, M, 128, 512);
  gat_agg_l3<<<nodeBlocks, 256, 0, stream>>>(b.R2f, aS3, aD3, b.start, b.cnt,
                                             b.csr, b3, b.R1f, M);
}
}  // namespace

extern "C" void kernel_launch(void* const* d_in, const int* in_sizes, int n_in,
                              void* d_out, int out_size, void* d_ws, size_t ws_size,
                              hipStream_t stream) {
  (void)in_sizes; (void)n_in; (void)out_size;
  const float* W1 = (const float*)d_in[6];
  const float* W2 = (const float*)d_in[10];
  const float* W3 = (const float*)d_in[14];
  const float* mw1 = (const float*)d_in[18];
  const float* mb1 = (const float*)d_in[19];
  const float* mw2 = (const float*)d_in[20];
  const float* mb2 = (const float*)d_in[21];

  // Prefer combined (both encoders batched, M=2N) if it fits the workspace.
  Bufs bc = plan(d_ws, 2 * kN, 2 * kE2);
  const bool combined = bc.need <= ws_size;
  Bufs b = combined ? bc : plan(d_ws, kN, kE2);

  const int wtot = 64 * 512 + 512 * 512 + 512 * 128;
  wt_split_all<<<(wtot + 255) / 256, 256, 0, stream>>>(W1, b.Wth1, W2, b.Wth2, W3,
                                                       b.Wth3);
  if (combined) {
    const int M = 2 * kN;
    const int* ei0 = (const int*)d_in[1];
    const int* ei1 = (const int*)d_in[4];
    prep2<<<(2 * kN * 64 + 255) / 256, 256, 0, stream>>>(
        (const float*)d_in[0], (const float*)d_in[3], b.R1h, b.cnt, b.total,
        b.alpha, M * 18);
    count_edges2<<<(2 * kE + 255) / 256, 256, 0, stream>>>(ei0 + kE, ei1 + kE,
                                                           b.cnt);
    alloc_ranges<<<(M + 255) / 256, 256, 0, stream>>>(b.cnt, b.start, b.cursor,
                                                      b.total, b.csr, M);
    fill_edges2<<<(2 * kE + 255) / 256, 256, 0, stream>>>(ei0, ei0 + kE, ei1,
                                                          ei1 + kE, b.cursor, b.csr);
    run_layers(b, d_in, M, stream);
    pool_max2<<<2 * kG, 128, 0, stream>>>(b.R1f, (const int*)d_in[2],
                                          (const int*)d_in[5], b.emb);
  } else {
    for (int enc = 0; enc < 2; ++enc) {
      const float* x = (const float*)d_in[enc * 3 + 0];
      const int* ei = (const int*)d_in[enc * 3 + 1];
      const int* batch = (const int*)d_in[enc * 3 + 2];
      prep<<<(kN * 64 + 255) / 256, 256, 0, stream>>>(x, b.R1h, b.cnt, b.total,
                                                      kN * 64, kN, b.alpha,
                                                      kN * 18);
      count_edges<<<(kE + 255) / 256, 256, 0, stream>>>(ei + kE, b.cnt, kE);
      alloc_ranges<<<(kN + 255) / 256, 256, 0, stream>>>(b.cnt, b.start, b.cursor,
                                                         b.total, b.csr, kN);
      fill_edges<<<(kE + 255) / 256, 256, 0, stream>>>(ei, ei + kE, b.cursor, b.csr,
                                                       kE);
      run_layers(b, d_in, kN, stream);
      pool_max<<<kG, 128, 0, stream>>>(b.R1f, batch, b.emb + (size_t)enc * kG * 128,
                                       kN);
    }
  }
  mlp_head<<<kG, 128, 0, stream>>>(b.emb, b.emb + (size_t)kG * 128, mw1, mb1, mw2,
                                   mb2, (float*)d_out);
}